// Round 5
// baseline (42.207 us; speedup 1.0000x reference)
//
#include <hip/hip_runtime.h>

typedef short short8 __attribute__((ext_vector_type(8)));
typedef float f32x4 __attribute__((ext_vector_type(4)));

static __device__ __forceinline__ unsigned short f2bf(float f) {
    unsigned u = __builtin_bit_cast(unsigned, f);
    u += 0x7FFFu + ((u >> 16) & 1u);   // RNE
    return (unsigned short)(u >> 16);
}

// ws layout (fragment-major, verified in rounds 3/4):
//   [0,128K)    Btg  bf16: element (n,k) of Wp^T at
//               idx = (k>>5)*8192 + (n>>4)*512 + (n&15)*32 + (k&31)
//   [128K,256K) injT bf16 per b: element (col,n) at
//               idx = b*8192 + (col>>4)*512 + (col&15)*32 + n   (n=16..31 zero)
//   [256K,+64)  flags: [0] = Btg-producer count (16), [1] = injT count (128)
#define OFF_INJT (128 * 1024)
#define OFF_FLAG (256 * 1024)

__global__ __launch_bounds__(256)
void fused_one(const float* __restrict__ patches,
               const float* __restrict__ embs,
               const int* __restrict__ locations,
               const float* __restrict__ Wp,
               const float* __restrict__ We,
               unsigned short* __restrict__ Btg,
               unsigned short* __restrict__ injT,
               unsigned* __restrict__ flags,
               float* __restrict__ out) {
    __shared__ float sh[64 * 65];
    __shared__ unsigned maskL[16];
    __shared__ float rcL[16];

    const int bid = blockIdx.x, t = threadIdx.x;
    unsigned* flagB = flags + 0;
    unsigned* flagI = flags + 1;

    // ================= producer roles (blocks 0..143) =================
    if (bid < 128) {
        // inj row (b2, n): (embs_ext[b2] @ We)[n,:] -> injT fragment-major bf16
        const int b2 = bid >> 4, n = bid & 15;
        float e;
        if (n == 15) {
            float s = 0.f;
            #pragma unroll
            for (int j = 0; j < 15; ++j) s += embs[(b2 * 15 + j) * 256 + t];
            e = s * (1.0f / 15.0f);
        } else {
            e = embs[(b2 * 15 + n) * 256 + t];
        }
        sh[t] = e;
        __syncthreads();
        float s0 = 0.f, s1 = 0.f, s2 = 0.f, s3 = 0.f;
        #pragma unroll 8
        for (int k0 = 0; k0 < 256; k0 += 4) {
            float4 e4 = *reinterpret_cast<const float4*>(&sh[k0]);
            s0 += e4.x * We[(k0 + 0) * 256 + t];
            s1 += e4.y * We[(k0 + 1) * 256 + t];
            s2 += e4.z * We[(k0 + 2) * 256 + t];
            s3 += e4.w * We[(k0 + 3) * 256 + t];
        }
        float acc = (s0 + s1) + (s2 + s3);
        int base = b2 * 8192 + (t >> 4) * 512 + (t & 15) * 32;
        injT[base + n] = f2bf(acc);
        if (n == 15) {  // zero pad n=16..31
            uint4 z = {0, 0, 0, 0};
            *reinterpret_cast<uint4*>(&injT[base + 16]) = z;
            *reinterpret_cast<uint4*>(&injT[base + 24]) = z;
        }
        __syncthreads();   // all waves' stores drained (vmcnt(0) before barrier)
        if (t == 0) {
            __threadfence();
            __hip_atomic_fetch_add(flagI, 1u, __ATOMIC_RELEASE, __HIP_MEMORY_SCOPE_AGENT);
        }
    } else if (bid < 144) {
        // 64x64 transpose tile of Wp -> Btg (fragment-major bf16)
        const int tt = bid - 128;
        const int kt = (tt >> 2) * 64, n0 = (tt & 3) * 64;
        #pragma unroll
        for (int it = 0; it < 16; ++it) {
            int u = t + it * 256;
            int kl = u >> 6, nl = u & 63;
            sh[kl * 65 + nl] = Wp[(kt + kl) * 256 + n0 + nl];
        }
        __syncthreads();
        #pragma unroll
        for (int it = 0; it < 4; ++it) {
            int v = t + it * 256;
            int nl = v >> 4, kg = v & 15;   // k = kt + kg*4 + c, c = 0..3
            ushort4 o;
            o.x = f2bf(sh[(kg * 4 + 0) * 65 + nl]);
            o.y = f2bf(sh[(kg * 4 + 1) * 65 + nl]);
            o.z = f2bf(sh[(kg * 4 + 2) * 65 + nl]);
            o.w = f2bf(sh[(kg * 4 + 3) * 65 + nl]);
            int ks = (kt >> 5) + (kg >> 3);
            int n16 = (n0 >> 4) + (nl >> 4);
            int idx = ks * 8192 + n16 * 512 + (nl & 15) * 32 + ((kg >> 1) & 3) * 8 + (kg & 1) * 4;
            *reinterpret_cast<ushort4*>(&Btg[idx]) = o;
        }
        __syncthreads();
        if (t == 0) {
            __threadfence();
            __hip_atomic_fetch_add(flagB, 1u, __ATOMIC_RELEASE, __HIP_MEMORY_SCOPE_AGENT);
        }
    }

    // ================= consumer (all 512 blocks) =================
    const int b = bid >> 6, p0 = (bid & 63) * 16;
    const int wv = t >> 6, lane = t & 63, lhi = lane >> 4, llo = lane & 15;

    if (t < 16) {
        int p = p0 + t;
        int h = p >> 5, w = p & 31;
        const int* loc = locations + b * 60;
        unsigned m = 1u << 15;  // full-image box always contains
        #pragma unroll
        for (int nb = 0; nb < 15; ++nb) {
            int y0 = loc[nb * 4 + 0] & ~1;
            int x0 = loc[nb * 4 + 1] & ~1;
            int y1 = (loc[nb * 4 + 2] & ~1) + 2;
            int x1 = (loc[nb * 4 + 3] & ~1) + 2;
            if (h >= y0 && h < y1 && w >= x0 && w < x1) m |= 1u << nb;
        }
        maskL[t] = m;
        rcL[t] = 1.0f / (float)__popc(m);
    }

    // A fragments straight from HBM (independent of prep -> overlaps it)
    const float* arow = patches + (size_t)(b * 1024 + p0 + llo) * 256;
    float4 a0[8], a1[8];
    #pragma unroll
    for (int ks = 0; ks < 8; ++ks) {
        a0[ks] = *reinterpret_cast<const float4*>(arow + ks * 32 + lhi * 8);
        a1[ks] = *reinterpret_cast<const float4*>(arow + ks * 32 + lhi * 8 + 4);
    }
    short8 af[8];
    #pragma unroll
    for (int ks = 0; ks < 8; ++ks) {
        short8 a;
        a[0] = (short)f2bf(a0[ks].x); a[1] = (short)f2bf(a0[ks].y);
        a[2] = (short)f2bf(a0[ks].z); a[3] = (short)f2bf(a0[ks].w);
        a[4] = (short)f2bf(a1[ks].x); a[5] = (short)f2bf(a1[ks].y);
        a[6] = (short)f2bf(a1[ks].z); a[7] = (short)f2bf(a1[ks].w);
        af[ks] = a;
    }

    // ---- gate 1: Btg ready (16 fast producers) ----
    if (t == 0) {
        int guard = 0;
        while (__hip_atomic_load(flagB, __ATOMIC_RELAXED, __HIP_MEMORY_SCOPE_AGENT) < 16u
               && ++guard < (1 << 24))
            __builtin_amdgcn_s_sleep(2);
        (void)__hip_atomic_load(flagB, __ATOMIC_ACQUIRE, __HIP_MEMORY_SCOPE_AGENT);
    }
    __syncthreads();

    // proj GEMM: B fragment loads are 1KB contiguous per wave (L2-resident)
    f32x4 acc[4];
    #pragma unroll
    for (int nt = 0; nt < 4; ++nt) acc[nt] = (f32x4){0.f, 0.f, 0.f, 0.f};
    #pragma unroll
    for (int ks = 0; ks < 8; ++ks) {
        #pragma unroll
        for (int nt = 0; nt < 4; ++nt) {
            const short8 bf = *reinterpret_cast<const short8*>(
                Btg + ks * 8192 + (wv * 4 + nt) * 512 + llo * 32 + lhi * 8);
            acc[nt] = __builtin_amdgcn_mfma_f32_16x16x32_bf16(af[ks], bf, acc[nt], 0, 0, 0);
        }
    }

    // ---- gate 2: injT ready (128 producers; GEMM above covered their tail) ----
    if (t == 0) {
        int guard = 0;
        while (__hip_atomic_load(flagI, __ATOMIC_RELAXED, __HIP_MEMORY_SCOPE_AGENT) < 128u
               && ++guard < (1 << 24))
            __builtin_amdgcn_s_sleep(2);
        (void)__hip_atomic_load(flagI, __ATOMIC_ACQUIRE, __HIP_MEMORY_SCOPE_AGENT);
    }
    __syncthreads();

    // epilogue: pooled masked-inj via one MFMA layer
    unsigned m = maskL[llo];
    short8 mfrag;
    #pragma unroll
    for (int r = 0; r < 8; ++r) {
        int k = lhi * 8 + r;
        mfrag[r] = (k < 16 && ((m >> k) & 1u)) ? (short)0x3F80 : (short)0;
    }
    f32x4 accE[4];
    #pragma unroll
    for (int nt = 0; nt < 4; ++nt) {
        const short8 jf = *reinterpret_cast<const short8*>(
            injT + b * 8192 + (wv * 4 + nt) * 512 + llo * 32 + lhi * 8);
        accE[nt] = __builtin_amdgcn_mfma_f32_16x16x32_bf16(
            mfrag, jf, (f32x4){0.f, 0.f, 0.f, 0.f}, 0, 0, 0);
    }

    float rc[4];
    #pragma unroll
    for (int j = 0; j < 4; ++j) rc[j] = rcL[lhi * 4 + j];

    float* ob = out + ((size_t)b * 1024 + p0) * 256;
    #pragma unroll
    for (int nt = 0; nt < 4; ++nt)
        #pragma unroll
        for (int j = 0; j < 4; ++j)
            ob[(lhi * 4 + j) * 256 + wv * 64 + nt * 16 + llo] = acc[nt][j] + rc[j] * accE[nt][j];
}

extern "C" void kernel_launch(void* const* d_in, const int* in_sizes, int n_in,
                              void* d_out, int out_size, void* d_ws, size_t ws_size,
                              hipStream_t stream) {
    const float* patches = (const float*)d_in[0];
    const float* embs    = (const float*)d_in[1];
    const int*   locs    = (const int*)d_in[2];
    const float* Wp      = (const float*)d_in[3];
    const float* We      = (const float*)d_in[4];
    float* out = (float*)d_out;

    unsigned short* Btg   = (unsigned short*)d_ws;
    unsigned short* injT  = (unsigned short*)((char*)d_ws + OFF_INJT);
    unsigned*       flags = (unsigned*)((char*)d_ws + OFF_FLAG);

    // reset the producer-done counters every call (survives the 0xAA poison,
    // keeps the launch deterministic; async memset is graph-capturable)
    hipMemsetAsync(flags, 0, 64, stream);
    fused_one<<<512, 256, 0, stream>>>(patches, embs, locs, Wp, We,
                                       Btg, injT, flags, out);
}

// Round 6
// 19.592 us; speedup vs baseline: 2.1543x; 2.1543x over previous
//
#include <hip/hip_runtime.h>

typedef short short8 __attribute__((ext_vector_type(8)));
typedef float f32x4 __attribute__((ext_vector_type(4)));

static __device__ __forceinline__ unsigned short f2bf(float f) {
    unsigned u = __builtin_bit_cast(unsigned, f);
    u += 0x7FFFu + ((u >> 16) & 1u);   // RNE
    return (unsigned short)(u >> 16);
}
static __device__ __forceinline__ float bf2f(unsigned short h) {
    unsigned u = ((unsigned)h) << 16;
    return __builtin_bit_cast(float, u);
}

// ws layout (fragment-major, verified rounds 3/4):
//   [0,128K)    Btg  bf16: element (n,k) of Wp^T at
//               idx = (k>>5)*8192 + (n>>4)*512 + (n&15)*32 + (k&31)
//   [128K,256K) injT bf16 per b: element (col,n) at
//               idx = b*8192 + (col>>4)*512 + (col&15)*32 + n   (n=16..31 zero)
#define OFF_INJT (128 * 1024)

// Prep v2: blocks 0..15  -> Wp^T 64x64 transpose tiles -> Btg (as rounds 3/4)
//          blocks 16..47 -> inj via MFMA: (b, 64-col slice); each wave = 16 cols
__global__ __launch_bounds__(256)
void prep_kernel(const float* __restrict__ embs,
                 const float* __restrict__ Wp,
                 const float* __restrict__ We,
                 unsigned short* __restrict__ Btg,
                 unsigned short* __restrict__ injT) {
    __shared__ float sh[64 * 65];
    __shared__ unsigned short Ebf[16 * 256];  // bf16, rows XOR-swizzled

    const int bid = blockIdx.x, t = threadIdx.x;

    if (bid < 16) {
        // ---- Wp^T transpose tile (verified) ----
        const int kt = (bid >> 2) * 64, n0 = (bid & 3) * 64;
        #pragma unroll
        for (int it = 0; it < 16; ++it) {
            int u = t + it * 256;
            int kl = u >> 6, nl = u & 63;
            sh[kl * 65 + nl] = Wp[(kt + kl) * 256 + n0 + nl];
        }
        __syncthreads();
        #pragma unroll
        for (int it = 0; it < 4; ++it) {
            int v = t + it * 256;
            int nl = v >> 4, kg = v & 15;   // k = kt + kg*4 + c
            ushort4 o;
            o.x = f2bf(sh[(kg * 4 + 0) * 65 + nl]);
            o.y = f2bf(sh[(kg * 4 + 1) * 65 + nl]);
            o.z = f2bf(sh[(kg * 4 + 2) * 65 + nl]);
            o.w = f2bf(sh[(kg * 4 + 3) * 65 + nl]);
            int ks = (kt >> 5) + (kg >> 3);
            int n16 = (n0 >> 4) + (nl >> 4);
            int idx = ks * 8192 + n16 * 512 + (nl & 15) * 32 + ((kg >> 1) & 3) * 8 + (kg & 1) * 4;
            *reinterpret_cast<ushort4*>(&Btg[idx]) = o;
        }
    } else {
        // ---- inj = E_ext[16x256] @ We[256x256], 64-col slice, via MFMA ----
        const int ib = bid - 16;
        const int b = ib >> 2, oq = ib & 3;

        // stage E bf16 swizzled: byte(r,c) = r*512 + ((c*2) ^ ((r&7)<<4))
        if (t < 128) {
            const int c0 = t * 2;
            #pragma unroll
            for (int r = 0; r < 15; ++r) {
                float2 v = *reinterpret_cast<const float2*>(embs + (size_t)(b * 15 + r) * 256 + c0);
                unsigned pk = (unsigned)f2bf(v.x) | ((unsigned)f2bf(v.y) << 16);
                *reinterpret_cast<unsigned*>(reinterpret_cast<char*>(Ebf)
                    + r * 512 + ((c0 * 2) ^ ((r & 7) << 4))) = pk;
            }
        }
        __syncthreads();
        if (t < 128) {   // mean row 15 (from bf16 rows, f32 accumulate)
            const int c0 = t * 2;
            float s0 = 0.f, s1 = 0.f;
            #pragma unroll
            for (int r = 0; r < 15; ++r) {
                unsigned pk = *reinterpret_cast<const unsigned*>(reinterpret_cast<char*>(Ebf)
                    + r * 512 + ((c0 * 2) ^ ((r & 7) << 4)));
                s0 += bf2f((unsigned short)(pk & 0xffffu));
                s1 += bf2f((unsigned short)(pk >> 16));
            }
            unsigned pk = (unsigned)f2bf(s0 * (1.0f / 15.0f))
                        | ((unsigned)f2bf(s1 * (1.0f / 15.0f)) << 16);
            *reinterpret_cast<unsigned*>(reinterpret_cast<char*>(Ebf)
                + 15 * 512 + ((c0 * 2) ^ ((7) << 4))) = pk;
        }
        __syncthreads();

        const int wv = t >> 6, lane = t & 63, lhi = lane >> 4, llo = lane & 15;
        const int oc = oq * 64 + wv * 16 + llo;   // output column this lane owns

        f32x4 acc = (f32x4){0.f, 0.f, 0.f, 0.f};
        #pragma unroll
        for (int ks = 0; ks < 8; ++ks) {
            // A-frag: E[row=llo][k = ks*32 + lhi*8 + r]  (swizzled b128)
            const short8 afr = *reinterpret_cast<const short8*>(
                reinterpret_cast<const char*>(Ebf)
                + llo * 512 + ((ks * 64 + lhi * 16) ^ ((llo & 7) << 4)));
            // B-frag: We[k][oc] gather (8 x stride-1KB dword, 16-lane coalesced)
            short8 bfr;
            #pragma unroll
            for (int r = 0; r < 8; ++r)
                bfr[r] = (short)f2bf(We[(size_t)(ks * 32 + lhi * 8 + r) * 256 + oc]);
            acc = __builtin_amdgcn_mfma_f32_16x16x32_bf16(afr, bfr, acc, 0, 0, 0);
        }
        // C: row n = lhi*4+j, col = oc  -> injT fragment-major + zero-pad
        ushort4 o4;
        o4.x = f2bf(acc[0]); o4.y = f2bf(acc[1]);
        o4.z = f2bf(acc[2]); o4.w = f2bf(acc[3]);
        unsigned short* dst = injT + (size_t)b * 8192 + (oq * 4 + wv) * 512 + llo * 32;
        *reinterpret_cast<ushort4*>(dst + lhi * 4) = o4;
        ushort4 z = {0, 0, 0, 0};
        *reinterpret_cast<ushort4*>(dst + 16 + lhi * 4) = z;
    }
}

// Fused (unchanged from round 4): block = (b, 16-pixel tile), 4 waves, no LDS
// staging of A/B, no hot-path barriers, all loads coalesced.
__global__ __launch_bounds__(256)
void fused_kernel(const float* __restrict__ patches,
                  const int* __restrict__ locations,
                  const unsigned short* __restrict__ Btg,
                  const unsigned short* __restrict__ injT,
                  float* __restrict__ out) {
    __shared__ unsigned maskL[16];
    __shared__ float rcL[16];

    const int bid = blockIdx.x, t = threadIdx.x;
    const int b = bid >> 6, p0 = (bid & 63) * 16;
    const int wv = t >> 6, lane = t & 63, lhi = lane >> 4, llo = lane & 15;

    if (t < 16) {
        int p = p0 + t;
        int h = p >> 5, w = p & 31;
        const int* loc = locations + b * 60;
        unsigned m = 1u << 15;  // full-image box always contains
        #pragma unroll
        for (int nb = 0; nb < 15; ++nb) {
            int y0 = loc[nb * 4 + 0] & ~1;
            int x0 = loc[nb * 4 + 1] & ~1;
            int y1 = (loc[nb * 4 + 2] & ~1) + 2;
            int x1 = (loc[nb * 4 + 3] & ~1) + 2;
            if (h >= y0 && h < y1 && w >= x0 && w < x1) m |= 1u << nb;
        }
        maskL[t] = m;
        rcL[t] = 1.0f / (float)__popc(m);
    }

    const float* arow = patches + (size_t)(b * 1024 + p0 + llo) * 256;
    float4 a0[8], a1[8];
    #pragma unroll
    for (int ks = 0; ks < 8; ++ks) {
        a0[ks] = *reinterpret_cast<const float4*>(arow + ks * 32 + lhi * 8);
        a1[ks] = *reinterpret_cast<const float4*>(arow + ks * 32 + lhi * 8 + 4);
    }
    short8 af[8];
    #pragma unroll
    for (int ks = 0; ks < 8; ++ks) {
        short8 a;
        a[0] = (short)f2bf(a0[ks].x); a[1] = (short)f2bf(a0[ks].y);
        a[2] = (short)f2bf(a0[ks].z); a[3] = (short)f2bf(a0[ks].w);
        a[4] = (short)f2bf(a1[ks].x); a[5] = (short)f2bf(a1[ks].y);
        a[6] = (short)f2bf(a1[ks].z); a[7] = (short)f2bf(a1[ks].w);
        af[ks] = a;
    }

    f32x4 acc[4];
    #pragma unroll
    for (int nt = 0; nt < 4; ++nt) acc[nt] = (f32x4){0.f, 0.f, 0.f, 0.f};
    #pragma unroll
    for (int ks = 0; ks < 8; ++ks) {
        #pragma unroll
        for (int nt = 0; nt < 4; ++nt) {
            const short8 bf = *reinterpret_cast<const short8*>(
                Btg + ks * 8192 + (wv * 4 + nt) * 512 + llo * 32 + lhi * 8);
            acc[nt] = __builtin_amdgcn_mfma_f32_16x16x32_bf16(af[ks], bf, acc[nt], 0, 0, 0);
        }
    }

    __syncthreads();  // maskL/rcL ready

    unsigned m = maskL[llo];
    short8 mfrag;
    #pragma unroll
    for (int r = 0; r < 8; ++r) {
        int k = lhi * 8 + r;
        mfrag[r] = (k < 16 && ((m >> k) & 1u)) ? (short)0x3F80 : (short)0;
    }
    f32x4 accE[4];
    #pragma unroll
    for (int nt = 0; nt < 4; ++nt) {
        const short8 jf = *reinterpret_cast<const short8*>(
            injT + b * 8192 + (wv * 4 + nt) * 512 + llo * 32 + lhi * 8);
        accE[nt] = __builtin_amdgcn_mfma_f32_16x16x32_bf16(
            mfrag, jf, (f32x4){0.f, 0.f, 0.f, 0.f}, 0, 0, 0);
    }

    float rc[4];
    #pragma unroll
    for (int j = 0; j < 4; ++j) rc[j] = rcL[lhi * 4 + j];

    float* ob = out + ((size_t)b * 1024 + p0) * 256;
    #pragma unroll
    for (int nt = 0; nt < 4; ++nt)
        #pragma unroll
        for (int j = 0; j < 4; ++j)
            ob[(lhi * 4 + j) * 256 + wv * 64 + nt * 16 + llo] = acc[nt][j] + rc[j] * accE[nt][j];
}

extern "C" void kernel_launch(void* const* d_in, const int* in_sizes, int n_in,
                              void* d_out, int out_size, void* d_ws, size_t ws_size,
                              hipStream_t stream) {
    const float* patches = (const float*)d_in[0];
    const float* embs    = (const float*)d_in[1];
    const int*   locs    = (const int*)d_in[2];
    const float* Wp      = (const float*)d_in[3];
    const float* We      = (const float*)d_in[4];
    float* out = (float*)d_out;

    unsigned short* Btg  = (unsigned short*)d_ws;
    unsigned short* injT = (unsigned short*)((char*)d_ws + OFF_INJT);

    prep_kernel<<<48, 256, 0, stream>>>(embs, Wp, We, Btg, injT);
    fused_kernel<<<512, 256, 0, stream>>>(patches, locs, Btg, injT, out);
}